// Round 10
// baseline (92.511 us; speedup 1.0000x reference)
//
#include <hip/hip_runtime.h>
#include <math.h>

#define NN 8192
#define DD 512
#define MM 4
#define EE 131072
#define NB 4    // batches of 16 pairs per wave

typedef float  floatx2 __attribute__((ext_vector_type(2)));
typedef _Float16 h2    __attribute__((ext_vector_type(2)));
typedef _Float16 f16x8 __attribute__((ext_vector_type(8)));
typedef float  f32x4   __attribute__((ext_vector_type(4)));

union F8U { f16x8 v; h2 h[4]; uint2 u2[2]; };

__device__ inline h2 pkrtz(float a, float b) {
    return __builtin_bit_cast(h2, __builtin_amdgcn_cvt_pkrtz(a, b));
}

__device__ inline float fdot2a(h2 a, h2 b, float c) {
#if __has_builtin(__builtin_amdgcn_fdot2)
    return __builtin_amdgcn_fdot2(a, b, c, false);
#else
    return c + (float)a[0] * (float)b[0] + (float)a[1] * (float)b[1];
#endif
}

// Dequant 8 fp8 (uint2) -> f16x8. Exact (e4m3 subset of f16).
__device__ inline f16x8 deq8v(uint2 u) {
    F8U o;
    floatx2 f;
    f = __builtin_amdgcn_cvt_pk_f32_fp8((int)u.x, false); o.h[0] = pkrtz(f[0], f[1]);
    f = __builtin_amdgcn_cvt_pk_f32_fp8((int)u.x, true);  o.h[1] = pkrtz(f[0], f[1]);
    f = __builtin_amdgcn_cvt_pk_f32_fp8((int)u.y, false); o.h[2] = pkrtz(f[0], f[1]);
    f = __builtin_amdgcn_cvt_pk_f32_fp8((int)u.y, true);  o.h[3] = pkrtz(f[0], f[1]);
    return o.v;
}

template <int CTRL>
__device__ inline float dpp_add(float v) {
    int x = __builtin_amdgcn_update_dpp(0, __builtin_bit_cast(int, v), CTRL, 0xf, 0xf, true);
    return v + __builtin_bit_cast(float, x);
}

// ---------------------------------------------------------------------------
// Kernel 1: quantize emb rows to fp8 e4m3 in FRAGMENT-MAJOR layout
// (uint2 slot within row = (lane&3)*16 + (lane>>2), i.e. byte kq*128+kk*8),
// and compute reciprocal norms from the SAME dequantized f16 values and
// pkrtz'd squared weights the pair kernel uses. rn transposed: rn_t[m][n].
// ---------------------------------------------------------------------------
__global__ __launch_bounds__(256) void quant_norm_kernel(const float* __restrict__ emb,
                                                         const float* __restrict__ mh,
                                                         uint2* __restrict__ q,
                                                         float* __restrict__ rn_t,
                                                         float* __restrict__ out) {
    if (blockIdx.x == 0 && threadIdx.x == 0) out[0] = 0.0f;

    const int lane = threadIdx.x & 63;
    const unsigned n = blockIdx.x * 4 + (threadIdx.x >> 6);

    const float* er = emb + n * DD + lane * 8;
    float4 e0 = *(const float4*)(er);
    float4 e1 = *(const float4*)(er + 4);

    int lo = 0, hi = 0;
    lo = __builtin_amdgcn_cvt_pk_fp8_f32(e0.x, e0.y, lo, false);
    lo = __builtin_amdgcn_cvt_pk_fp8_f32(e0.z, e0.w, lo, true);
    hi = __builtin_amdgcn_cvt_pk_fp8_f32(e1.x, e1.y, hi, false);
    hi = __builtin_amdgcn_cvt_pk_fp8_f32(e1.z, e1.w, hi, true);

    uint2 u = make_uint2((unsigned)lo, (unsigned)hi);
    // fragment-major slot: kq = lane&3, kk = lane>>2
    q[(n << 6) | (((unsigned)(lane & 3) << 4) | ((unsigned)lane >> 2))] = u;

    F8U A; A.v = deq8v(u);
    h2 p0 = A.h[0] * A.h[0];
    h2 p1 = A.h[1] * A.h[1];
    h2 p2 = A.h[2] * A.h[2];
    h2 p3 = A.h[3] * A.h[3];

    const float* mb = mh + lane * 8;
    float ss[4];
    #pragma unroll
    for (int m = 0; m < 4; ++m) {
        float4 m0 = *(const float4*)(mb + m * DD);
        float4 m1 = *(const float4*)(mb + m * DD + 4);
        h2 w0 = pkrtz(m0.x * m0.x, m0.y * m0.y);
        h2 w1 = pkrtz(m0.z * m0.z, m0.w * m0.w);
        h2 w2 = pkrtz(m1.x * m1.x, m1.y * m1.y);
        h2 w3 = pkrtz(m1.z * m1.z, m1.w * m1.w);
        float s = 0.f;
        s = fdot2a(p0, w0, s);
        s = fdot2a(p1, w1, s);
        s = fdot2a(p2, w2, s);
        s = fdot2a(p3, w3, s);
        ss[m] = s;
    }

    ss[0] = dpp_add<0x111>(ss[0]); ss[1] = dpp_add<0x111>(ss[1]);
    ss[2] = dpp_add<0x111>(ss[2]); ss[3] = dpp_add<0x111>(ss[3]);
    ss[0] = dpp_add<0x112>(ss[0]); ss[1] = dpp_add<0x112>(ss[1]);
    ss[2] = dpp_add<0x112>(ss[2]); ss[3] = dpp_add<0x112>(ss[3]);
    ss[0] = dpp_add<0x114>(ss[0]); ss[1] = dpp_add<0x114>(ss[1]);
    ss[2] = dpp_add<0x114>(ss[2]); ss[3] = dpp_add<0x114>(ss[3]);
    ss[0] = dpp_add<0x118>(ss[0]); ss[1] = dpp_add<0x118>(ss[1]);
    ss[2] = dpp_add<0x118>(ss[2]); ss[3] = dpp_add<0x118>(ss[3]);
    ss[0] = dpp_add<0x142>(ss[0]); ss[1] = dpp_add<0x142>(ss[1]);
    ss[2] = dpp_add<0x142>(ss[2]); ss[3] = dpp_add<0x142>(ss[3]);
    ss[0] = dpp_add<0x143>(ss[0]); ss[1] = dpp_add<0x143>(ss[1]);
    ss[2] = dpp_add<0x143>(ss[2]); ss[3] = dpp_add<0x143>(ss[3]);

    if (lane == 63) {
        rn_t[0 * NN + n] = 1.0f / fmaxf(sqrtf(ss[0]), 1e-12f);
        rn_t[1 * NN + n] = 1.0f / fmaxf(sqrtf(ss[1]), 1e-12f);
        rn_t[2 * NN + n] = 1.0f / fmaxf(sqrtf(ss[2]), 1e-12f);
        rn_t[3 * NN + n] = 1.0f / fmaxf(sqrtf(ss[3]), 1e-12f);
    }
}

// ---------------------------------------------------------------------------
// Kernel 2: MFMA pair kernel, register-staged 2-deep pipeline (round-7
// structure), fragment-major fp8 gathers (8x dwordx4 per row side per lane).
// B-operand squared weights in LDS (round-8-verified layout). 4 waves/block.
// ---------------------------------------------------------------------------
struct Batch {
    uint4 a[8], b[8];
    float ra[4], rb[4];
};

__device__ inline void load_batch(Batch& B, const int* __restrict__ eb, int lb2,
                                  const unsigned char* __restrict__ qtab,
                                  const float* __restrict__ rm, int p, int kq) {
    int i = eb[lb2 + p];
    int j = eb[lb2 + EE + p];
    const unsigned char* qi = qtab + ((size_t)(unsigned)i << 9) + kq * 128;
    const unsigned char* qj = qtab + ((size_t)(unsigned)j << 9) + kq * 128;
    #pragma unroll
    for (int c = 0; c < 8; ++c) {
        B.a[c] = *(const uint4*)(qi + c * 16);
        B.b[c] = *(const uint4*)(qj + c * 16);
    }
    int4 pi = *(const int4*)(eb + lb2 + kq * 4);
    int4 pj = *(const int4*)(eb + lb2 + EE + kq * 4);
    B.ra[0] = rm[pi.x]; B.rb[0] = rm[pj.x];
    B.ra[1] = rm[pi.y]; B.rb[1] = rm[pj.y];
    B.ra[2] = rm[pi.z]; B.rb[2] = rm[pj.z];
    B.ra[3] = rm[pi.w]; B.rb[3] = rm[pj.w];
}

__device__ inline float compute_batch(const Batch& B, const _Float16* wbase,
                                      bool pos, int p) {
    f32x4 acc = {0.f, 0.f, 0.f, 0.f};
    #pragma unroll
    for (int c = 0; c < 8; ++c) {
        uint2 ua0 = make_uint2(B.a[c].x, B.a[c].y);
        uint2 ub0 = make_uint2(B.b[c].x, B.b[c].y);
        F8U pa, pb, pr;
        pa.v = deq8v(ua0);
        pb.v = deq8v(ub0);
        pr.h[0] = pa.h[0] * pb.h[0];
        pr.h[1] = pa.h[1] * pb.h[1];
        pr.h[2] = pa.h[2] * pb.h[2];
        pr.h[3] = pa.h[3] * pb.h[3];
        acc = __builtin_amdgcn_mfma_f32_16x16x32_f16(pr.v, *(const f16x8*)(wbase + (2 * c) * 128),
                                                     acc, 0, 0, 0);
        uint2 ua1 = make_uint2(B.a[c].z, B.a[c].w);
        uint2 ub1 = make_uint2(B.b[c].z, B.b[c].w);
        pa.v = deq8v(ua1);
        pb.v = deq8v(ub1);
        pr.h[0] = pa.h[0] * pb.h[0];
        pr.h[1] = pa.h[1] * pb.h[1];
        pr.h[2] = pa.h[2] * pb.h[2];
        pr.h[3] = pa.h[3] * pb.h[3];
        acc = __builtin_amdgcn_mfma_f32_16x16x32_f16(pr.v, *(const f16x8*)(wbase + (2 * c + 1) * 128),
                                                     acc, 0, 0, 0);
    }

    float v0 = acc[0] * (B.ra[0] * B.rb[0]);
    float v1 = acc[1] * (B.ra[1] * B.rb[1]);
    float v2 = acc[2] * (B.ra[2] * B.rb[2]);
    float v3 = acc[3] * (B.ra[3] * B.rb[3]);
    v0 = dpp_add<0x111>(v0); v1 = dpp_add<0x111>(v1);
    v2 = dpp_add<0x111>(v2); v3 = dpp_add<0x111>(v3);
    v0 = dpp_add<0x112>(v0); v1 = dpp_add<0x112>(v1);
    v2 = dpp_add<0x112>(v2); v3 = dpp_add<0x112>(v3);
    // lane p==3 (per kq row) holds full m-sums for pairs kq*4 + 0..3

    float d0 = 1.000001f - 0.25f * v0;
    float d1 = 1.000001f - 0.25f * v1;
    float d2 = 1.000001f - 0.25f * v2;
    float d3 = 1.000001f - 0.25f * v3;
    float a0 = pos ? d0 : fmaf(-0.5f, d0, 1.0f);
    float a1 = pos ? d1 : fmaf(-0.5f, d1, 1.0f);
    float a2 = pos ? d2 : fmaf(-0.5f, d2, 1.0f);
    float a3 = pos ? d3 : fmaf(-0.5f, d3, 1.0f);
    float lg = __logf(fmaxf(a0, 1e-8f)) + __logf(fmaxf(a1, 1e-8f)) +
               __logf(fmaxf(a2, 1e-8f)) + __logf(fmaxf(a3, 1e-8f));
    return (p == 3) ? lg : 0.f;
}

__global__ __launch_bounds__(256, 2) void pair_kernel(const int* __restrict__ edges,
                                                      const int* __restrict__ nedges,
                                                      const unsigned char* __restrict__ qtab,
                                                      const float* __restrict__ mh,
                                                      const float* __restrict__ rn_t,
                                                      float* __restrict__ out) {
    __shared__ _Float16 wlds[2048];   // 4KB B-operand weights
    __shared__ float wsum[4];

    const int t = threadIdx.x;
    {   // stage squared f16 weights (round-8-verified layout)
        int m = t >> 6, sl = t & 63;
        const float* mb = mh + m * DD + sl * 8;
        float4 m0 = *(const float4*)(mb);
        float4 m1 = *(const float4*)(mb + 4);
        F8U wv;
        wv.h[0] = pkrtz(m0.x * m0.x, m0.y * m0.y);
        wv.h[1] = pkrtz(m0.z * m0.z, m0.w * m0.w);
        wv.h[2] = pkrtz(m1.x * m1.x, m1.y * m1.y);
        wv.h[3] = pkrtz(m1.z * m1.z, m1.w * m1.w);
        int s = (sl >> 2) * 16 + (sl & 3) * 4 + m;   // kk*16 + kq*4 + m
        *(f16x8*)(&wlds[s * 8]) = wv.v;
    }
    __syncthreads();

    const int lane   = t & 63;
    const int waveId = t >> 6;
    const int p  = lane & 15;
    const int kq = lane >> 4;
    const int m  = p & 3;
    const int gw = blockIdx.x * 4 + waveId;        // 4096 waves x 64 pairs

    const _Float16* wbase = &wlds[(kq * 4 + m) * 8];
    const float*    rm    = rn_t + m * NN;

    const int  base = gw * (NB * 16);
    const bool pos  = base < EE;
    const int* eb   = pos ? edges : nedges;
    const int  lb   = pos ? base : base - EE;

    Batch B0, B1;
    load_batch(B0, eb, lb,      qtab, rm, p, kq);
    load_batch(B1, eb, lb + 16, qtab, rm, p, kq);

    float lsum = compute_batch(B0, wbase, pos, p);
    load_batch(B0, eb, lb + 32, qtab, rm, p, kq);
    lsum += compute_batch(B1, wbase, pos, p);
    load_batch(B1, eb, lb + 48, qtab, rm, p, kq);
    lsum += compute_batch(B0, wbase, pos, p);
    lsum += compute_batch(B1, wbase, pos, p);

    // final 64-lane reduce (nonzero only in lanes 3,19,35,51)
    lsum = dpp_add<0x111>(lsum);
    lsum = dpp_add<0x112>(lsum);
    lsum = dpp_add<0x114>(lsum);
    lsum = dpp_add<0x118>(lsum);
    lsum = dpp_add<0x142>(lsum);
    lsum = dpp_add<0x143>(lsum);

    if (lane == 63) wsum[waveId] = lsum;
    __syncthreads();
    if (t == 0) {
        float s = wsum[0] + wsum[1] + wsum[2] + wsum[3];
        atomicAdd(out, -s);
    }
}

extern "C" void kernel_launch(void* const* d_in, const int* in_sizes, int n_in,
                              void* d_out, int out_size, void* d_ws, size_t ws_size,
                              hipStream_t stream) {
    const int*   edges  = (const int*)d_in[0];
    const int*   nedges = (const int*)d_in[1];
    const float* emb    = (const float*)d_in[2];
    const float* mh     = (const float*)d_in[3];
    float* out = (float*)d_out;

    uint2* q    = (uint2*)d_ws;                                  // 4 MiB fp8 table
    float* rn_t = (float*)((char*)d_ws + (size_t)NN * DD);       // 128 KiB, [m][n]

    quant_norm_kernel<<<NN / 4, 256, 0, stream>>>(emb, mh, q, rn_t, out);
    pair_kernel<<<(2 * EE) / (4 * NB * 16), 256, 0, stream>>>(edges, nedges,
                                                              (const unsigned char*)q,
                                                              mh, rn_t, out);
}

// Round 11
// 70.427 us; speedup vs baseline: 1.3136x; 1.3136x over previous
//
#include <hip/hip_runtime.h>
#include <math.h>

#define NN 8192
#define DD 512
#define MM 4
#define EE 131072
#define NB 8    // 16-pair batches per wave; 512 blocks x 4 waves x 8 x 16 = 262144

typedef float  floatx2 __attribute__((ext_vector_type(2)));
typedef _Float16 h2    __attribute__((ext_vector_type(2)));
typedef _Float16 f16x8 __attribute__((ext_vector_type(8)));
typedef float  f32x4   __attribute__((ext_vector_type(4)));

union F8U { f16x8 v; h2 h[4]; uint2 u2[2]; };

__device__ inline h2 pkrtz(float a, float b) {
    return __builtin_bit_cast(h2, __builtin_amdgcn_cvt_pkrtz(a, b));
}

__device__ inline float fdot2a(h2 a, h2 b, float c) {
#if __has_builtin(__builtin_amdgcn_fdot2)
    return __builtin_amdgcn_fdot2(a, b, c, false);
#else
    return c + (float)a[0] * (float)b[0] + (float)a[1] * (float)b[1];
#endif
}

// Dequant 8 fp8 e4m3 (uint2) -> f16x8. Exact (e4m3 subset of f16).
__device__ inline f16x8 deq8v(uint2 u) {
    F8U o;
    floatx2 f;
    f = __builtin_amdgcn_cvt_pk_f32_fp8((int)u.x, false); o.h[0] = pkrtz(f[0], f[1]);
    f = __builtin_amdgcn_cvt_pk_f32_fp8((int)u.x, true);  o.h[1] = pkrtz(f[0], f[1]);
    f = __builtin_amdgcn_cvt_pk_f32_fp8((int)u.y, false); o.h[2] = pkrtz(f[0], f[1]);
    f = __builtin_amdgcn_cvt_pk_f32_fp8((int)u.y, true);  o.h[3] = pkrtz(f[0], f[1]);
    return o.v;
}

template <int CTRL>
__device__ inline float dpp_add(float v) {
    int x = __builtin_amdgcn_update_dpp(0, __builtin_bit_cast(int, v), CTRL, 0xf, 0xf, true);
    return v + __builtin_bit_cast(float, x);
}

// ---------------------------------------------------------------------------
// Kernel 1 (r9-verified): quantize emb rows to fp8 e4m3 (ROW-LINEAR layout);
// reciprocal norms from the SAME dequantized f16 values / pkrtz'd squared
// weights the pair kernel uses. rn transposed rn_t[m][n]. Zeroes out[0].
// ---------------------------------------------------------------------------
__global__ __launch_bounds__(256) void quant_norm_kernel(const float* __restrict__ emb,
                                                         const float* __restrict__ mh,
                                                         uint2* __restrict__ q,
                                                         float* __restrict__ rn_t,
                                                         float* __restrict__ out) {
    if (blockIdx.x == 0 && threadIdx.x == 0) out[0] = 0.0f;

    const int lane = threadIdx.x & 63;
    const unsigned n = blockIdx.x * 4 + (threadIdx.x >> 6);

    const float* er = emb + n * DD + lane * 8;
    float4 e0 = *(const float4*)(er);
    float4 e1 = *(const float4*)(er + 4);

    int lo = 0, hi = 0;
    lo = __builtin_amdgcn_cvt_pk_fp8_f32(e0.x, e0.y, lo, false);
    lo = __builtin_amdgcn_cvt_pk_fp8_f32(e0.z, e0.w, lo, true);
    hi = __builtin_amdgcn_cvt_pk_fp8_f32(e1.x, e1.y, hi, false);
    hi = __builtin_amdgcn_cvt_pk_fp8_f32(e1.z, e1.w, hi, true);

    uint2 u = make_uint2((unsigned)lo, (unsigned)hi);
    q[(n << 6) | lane] = u;

    F8U A; A.v = deq8v(u);
    h2 p0 = A.h[0] * A.h[0];
    h2 p1 = A.h[1] * A.h[1];
    h2 p2 = A.h[2] * A.h[2];
    h2 p3 = A.h[3] * A.h[3];

    const float* mb = mh + lane * 8;
    float ss[4];
    #pragma unroll
    for (int m = 0; m < 4; ++m) {
        float4 m0 = *(const float4*)(mb + m * DD);
        float4 m1 = *(const float4*)(mb + m * DD + 4);
        h2 w0 = pkrtz(m0.x * m0.x, m0.y * m0.y);
        h2 w1 = pkrtz(m0.z * m0.z, m0.w * m0.w);
        h2 w2 = pkrtz(m1.x * m1.x, m1.y * m1.y);
        h2 w3 = pkrtz(m1.z * m1.z, m1.w * m1.w);
        float s = 0.f;
        s = fdot2a(p0, w0, s);
        s = fdot2a(p1, w1, s);
        s = fdot2a(p2, w2, s);
        s = fdot2a(p3, w3, s);
        ss[m] = s;
    }

    ss[0] = dpp_add<0x111>(ss[0]); ss[1] = dpp_add<0x111>(ss[1]);
    ss[2] = dpp_add<0x111>(ss[2]); ss[3] = dpp_add<0x111>(ss[3]);
    ss[0] = dpp_add<0x112>(ss[0]); ss[1] = dpp_add<0x112>(ss[1]);
    ss[2] = dpp_add<0x112>(ss[2]); ss[3] = dpp_add<0x112>(ss[3]);
    ss[0] = dpp_add<0x114>(ss[0]); ss[1] = dpp_add<0x114>(ss[1]);
    ss[2] = dpp_add<0x114>(ss[2]); ss[3] = dpp_add<0x114>(ss[3]);
    ss[0] = dpp_add<0x118>(ss[0]); ss[1] = dpp_add<0x118>(ss[1]);
    ss[2] = dpp_add<0x118>(ss[2]); ss[3] = dpp_add<0x118>(ss[3]);
    ss[0] = dpp_add<0x142>(ss[0]); ss[1] = dpp_add<0x142>(ss[1]);
    ss[2] = dpp_add<0x142>(ss[2]); ss[3] = dpp_add<0x142>(ss[3]);
    ss[0] = dpp_add<0x143>(ss[0]); ss[1] = dpp_add<0x143>(ss[1]);
    ss[2] = dpp_add<0x143>(ss[2]); ss[3] = dpp_add<0x143>(ss[3]);

    if (lane == 63) {
        rn_t[0 * NN + n] = 1.0f / fmaxf(sqrtf(ss[0]), 1e-12f);
        rn_t[1 * NN + n] = 1.0f / fmaxf(sqrtf(ss[1]), 1e-12f);
        rn_t[2 * NN + n] = 1.0f / fmaxf(sqrtf(ss[2]), 1e-12f);
        rn_t[3 * NN + n] = 1.0f / fmaxf(sqrtf(ss[3]), 1e-12f);
    }
}

// ---------------------------------------------------------------------------
// Kernel 2: MFMA with per-wave LDS product-transpose.
//  - r7-style coalesced row gathers (1 instr = 1 full 512B row) into regs
//  - dequant + pk_mul products in coalesced domain (f16, 16B/lane)
//  - ds_write_b128 per pair into private 16KB wave region, chunk ^= (pair&7)
//  - ds_read_b128 in fragment layout (chunk = mf*4+kq, same XOR) -> MFMA
//  - k-slot map: dim = mf*32 + kq*8 + e  (matches r9-verified bw[] layout)
//  - epilogue identical to r8-r10 (verified)
// ---------------------------------------------------------------------------
__global__ __launch_bounds__(256) void pair_kernel(const int* __restrict__ edges,
                                                   const int* __restrict__ nedges,
                                                   const uint2* __restrict__ q,
                                                   const float* __restrict__ mh,
                                                   const float* __restrict__ rn_t,
                                                   float* __restrict__ out) {
    __shared__ __align__(16) unsigned char plds[4][16384];   // 64 KiB

    const int t    = threadIdx.x;
    const int lane = t & 63;
    const int waveId = t >> 6;
    const int p  = lane & 15;     // pair-row / B-col
    const int kq = lane >> 4;     // k-quad
    const int m  = p & 3;

    unsigned char* wp = plds[waveId];

    // B-fragment weights in regs: bw[mf][e] = f16(mh[m][mf*32 + kq*8 + e]^2)
    const float* wsrc = mh + m * DD + kq * 8;
    f16x8 bw[16];
    #pragma unroll
    for (int kk = 0; kk < 16; ++kk) {
        float4 a = *(const float4*)(wsrc + kk * 32);
        float4 b = *(const float4*)(wsrc + kk * 32 + 4);
        F8U tw;
        tw.h[0] = pkrtz(a.x * a.x, a.y * a.y);
        tw.h[1] = pkrtz(a.z * a.z, a.w * a.w);
        tw.h[2] = pkrtz(b.x * b.x, b.y * b.y);
        tw.h[3] = pkrtz(b.z * b.z, b.w * b.w);
        bw[kk] = tw.v;
    }

    const int gw   = blockIdx.x * 4 + waveId;     // 2048 waves x 128 pairs
    const int base = gw * (NB * 16);
    const bool pos = base < EE;
    const int* eb  = pos ? edges : nedges;
    const int  lb  = pos ? base : base - EE;

    const float* rm = rn_t + m * NN;

    float lsum = 0.f;

    #pragma unroll 1
    for (int bt = 0; bt < NB; ++bt) {
        const int lb2 = lb + bt * 16;

        // ---- coalesced row gathers (uniform row index -> 1 instr/row) ----
        uint2 qa[16], qb[16];
        #pragma unroll
        for (int s = 0; s < 16; ++s) {
            int is = eb[lb2 + s];          // uniform -> s_load
            int js = eb[lb2 + EE + s];
            qa[s] = q[((unsigned)is << 6) | lane];
            qb[s] = q[((unsigned)js << 6) | lane];
        }

        // epilogue operands (overlap with compute)
        int4 pi4 = *(const int4*)(eb + lb2 + kq * 4);
        int4 pj4 = *(const int4*)(eb + lb2 + EE + kq * 4);
        float w0 = rm[pi4.x] * rm[pj4.x];
        float w1 = rm[pi4.y] * rm[pj4.y];
        float w2 = rm[pi4.z] * rm[pj4.z];
        float w3 = rm[pi4.w] * rm[pj4.w];

        // ---- products -> LDS (chunk-XOR swizzle, write side) ----
        #pragma unroll
        for (int s = 0; s < 16; ++s) {
            F8U pa, pb, pr;
            pa.v = deq8v(qa[s]);
            pb.v = deq8v(qb[s]);
            pr.h[0] = pa.h[0] * pb.h[0];
            pr.h[1] = pa.h[1] * pb.h[1];
            pr.h[2] = pa.h[2] * pb.h[2];
            pr.h[3] = pa.h[3] * pb.h[3];
            *(f16x8*)(&wp[(unsigned)(s * 1024 + ((lane * 16) ^ ((s & 7) << 4)))]) = pr.v;
        }

        // ---- fragment reads + MFMA (two 8-deep acc chains) ----
        f32x4 acc0 = {0.f, 0.f, 0.f, 0.f};
        f32x4 acc1 = {0.f, 0.f, 0.f, 0.f};
        #pragma unroll
        for (int mf = 0; mf < 16; mf += 2) {
            f16x8 av0 = *(const f16x8*)(&wp[(unsigned)(p * 1024 +
                            ((mf * 64 + kq * 16) ^ ((p & 7) << 4)))]);
            acc0 = __builtin_amdgcn_mfma_f32_16x16x32_f16(av0, bw[mf], acc0, 0, 0, 0);
            f16x8 av1 = *(const f16x8*)(&wp[(unsigned)(p * 1024 +
                            (((mf + 1) * 64 + kq * 16) ^ ((p & 7) << 4)))]);
            acc1 = __builtin_amdgcn_mfma_f32_16x16x32_f16(av1, bw[mf + 1], acc1, 0, 0, 0);
        }

        // ---- epilogue (r8-verified mapping) ----
        float v0 = (acc0[0] + acc1[0]) * w0;
        float v1 = (acc0[1] + acc1[1]) * w1;
        float v2 = (acc0[2] + acc1[2]) * w2;
        float v3 = (acc0[3] + acc1[3]) * w3;
        v0 = dpp_add<0x111>(v0); v1 = dpp_add<0x111>(v1);
        v2 = dpp_add<0x111>(v2); v3 = dpp_add<0x111>(v3);
        v0 = dpp_add<0x112>(v0); v1 = dpp_add<0x112>(v1);
        v2 = dpp_add<0x112>(v2); v3 = dpp_add<0x112>(v3);
        // lane p==3 (per kq row) holds full m-sums for pairs kq*4 + 0..3

        float d0 = 1.000001f - 0.25f * v0;
        float d1 = 1.000001f - 0.25f * v1;
        float d2 = 1.000001f - 0.25f * v2;
        float d3 = 1.000001f - 0.25f * v3;
        float a0 = pos ? d0 : fmaf(-0.5f, d0, 1.0f);
        float a1 = pos ? d1 : fmaf(-0.5f, d1, 1.0f);
        float a2 = pos ? d2 : fmaf(-0.5f, d2, 1.0f);
        float a3 = pos ? d3 : fmaf(-0.5f, d3, 1.0f);
        float lg = __logf(fmaxf(a0, 1e-8f)) + __logf(fmaxf(a1, 1e-8f)) +
                   __logf(fmaxf(a2, 1e-8f)) + __logf(fmaxf(a3, 1e-8f));
        lsum += (p == 3) ? lg : 0.f;
    }

    // final 64-lane reduce (nonzero only in lanes 3,19,35,51)
    lsum = dpp_add<0x111>(lsum);
    lsum = dpp_add<0x112>(lsum);
    lsum = dpp_add<0x114>(lsum);
    lsum = dpp_add<0x118>(lsum);
    lsum = dpp_add<0x142>(lsum);
    lsum = dpp_add<0x143>(lsum);

    if (lane == 63) atomicAdd(out, -lsum);
}

extern "C" void kernel_launch(void* const* d_in, const int* in_sizes, int n_in,
                              void* d_out, int out_size, void* d_ws, size_t ws_size,
                              hipStream_t stream) {
    const int*   edges  = (const int*)d_in[0];
    const int*   nedges = (const int*)d_in[1];
    const float* emb    = (const float*)d_in[2];
    const float* mh     = (const float*)d_in[3];
    float* out = (float*)d_out;

    uint2* q    = (uint2*)d_ws;                                  // 4 MiB fp8 table
    float* rn_t = (float*)((char*)d_ws + (size_t)NN * DD);       // 128 KiB, [m][n]

    quant_norm_kernel<<<NN / 4, 256, 0, stream>>>(emb, mh, q, rn_t, out);
    pair_kernel<<<(2 * EE) / (4 * NB * 16), 256, 0, stream>>>(edges, nedges, q,
                                                              mh, rn_t, out);
}